// Round 15
// baseline (1986.185 us; speedup 1.0000x reference)
//
#include <hip/hip_runtime.h>
#include <hip/hip_bf16.h>

#define B_   2048
#define V_   1024
#define H_   512
#define E_   256
#define L_   32

typedef __attribute__((ext_vector_type(4))) float f32x4;
typedef __attribute__((ext_vector_type(2))) long i64x2;
typedef unsigned short u16;
typedef unsigned int   u32;
typedef unsigned char  u8;
typedef unsigned long long u64;
typedef long long      i64;

__device__ __forceinline__ u32 f32b(float x){ union{float f;u32 u;}v; v.f=x; return v.u; }
__device__ __forceinline__ float bf32(u32 u){ union{float f;u32 u;}v; v.u=u; return v.f; }
__device__ __forceinline__ u16 f2bf(float x) {
    u32 u = f32b(x);
    u32 r = u + 0x7fffu + ((u >> 16) & 1u);
    return (u16)(r >> 16);
}
// OCP e4m3fn encode, RNE, flush below 2^-6
__device__ __forceinline__ u8 f2e4m3(float x) {
    u32 u = f32b(x);
    u32 s = (u >> 24) & 0x80u;
    u32 a = u & 0x7fffffffu;
    if (a < 0x3c800000u) return (u8)s;
    if (a > 0x43e00000u) a = 0x43e00000u;
    u32 r = a + 0x000fffffu + ((a >> 20) & 1u);
    if (r > 0x43e00000u) r = 0x43e00000u;
    u32 ex = (r >> 23) - 120u;
    u32 mn = (r >> 20) & 7u;
    return (u8)(s | (ex << 3) | mn);
}
__device__ __forceinline__ u8 f2fp8(float x) {
#if __has_builtin(__builtin_amdgcn_cvt_pk_fp8_f32)
    return (u8)(__builtin_amdgcn_cvt_pk_fp8_f32(x, x, 0, false) & 0xff);
#else
    return f2e4m3(x);
#endif
}
__device__ __forceinline__ float sig_(float x)  { return 1.f / (1.f + __expf(-x)); }
__device__ __forceinline__ float tanh_(float x) { return 1.f - 2.f / (__expf(2.f * x) + 1.f); }

__device__ __forceinline__ void ag_st64(void* p, u64 v) {
    __hip_atomic_store((u64*)p, v, __ATOMIC_RELAXED, __HIP_MEMORY_SCOPE_AGENT);
}
__device__ __forceinline__ u64 ag_ld64(const void* p) {
    return __hip_atomic_load((const u64*)p, __ATOMIC_RELAXED, __HIP_MEMORY_SCOPE_AGENT);
}
__device__ __forceinline__ void ag_st32(void* p, u32 v) {
    __hip_atomic_store((u32*)p, v, __ATOMIC_RELAXED, __HIP_MEMORY_SCOPE_AGENT);
}
__device__ __forceinline__ u32 ag_ld32(const void* p) {
    return __hip_atomic_load((const u32*)p, __ATOMIC_RELAXED, __HIP_MEMORY_SCOPE_AGENT);
}

// -------------------------------------------------------------------------
// Pair-split layouts (r12 geometry), re-ordered LANE-CONTIGUOUS for direct
// L2->VGPR streaming: lane l's dwordx4 = both jj fragments. fp8 e4m3 x64.
// Unit = 8 KB = 8 waves x 1 KB; wave slice at w*1024; lane slice at l*16.
//  w1f: [hb 2][ks 24][g 4][wv 8][l 64][jj 2][e 8]
//      k = ks*32+(l>>4)*8+e,  row = g*512 + hb*256 + wv*32 + jj*16 + (l&15)
//  wof: [hb 2][ks 16][vh2 2][wv 8][l 64][jj 2][e 8]
//      k = ks*32+(l>>4)*8+e,  v = hb*512 + vh2*256 + wv*32 + jj*16 + (l&15)
//  wef: [hb 2][ksp 16][wv 8][l 64][jj 2][e 8]
//      kv = hb*512 + ksp*32+(l>>4)*8+e,  ce = wv*32 + jj*16 + (l&15)
// -------------------------------------------------------------------------
__global__ void prep(const float* __restrict__ W_ih, const float* __restrict__ W_hh,
                     const float* __restrict__ b_ih, const float* __restrict__ b_hh,
                     const float* __restrict__ W_out, const float* __restrict__ W_emb,
                     u8* __restrict__ w1f, u8* __restrict__ wof, u8* __restrict__ wef,
                     float* __restrict__ b1, u32* __restrict__ flg)
{
    u32 idx = blockIdx.x * 256 + threadIdx.x;
    if (idx < 1572864u) {                      // W1-halves -> fp8*64
        u32 hb = idx / 786432u;
        u32 r  = idx - hb * 786432u;
        u32 ks = r >> 15;
        u32 r2 = r & 32767u;
        u32 g = r2 >> 13, wv = (r2 >> 10) & 7u, l = (r2 >> 4) & 63u,
            jj = (r2 >> 3) & 1u, e = r2 & 7u;
        u32 k = ks * 32u + ((l >> 4) << 3) + e;
        u32 row = g * 512u + hb * 256u + wv * 32u + jj * 16u + (l & 15u);
        float v = (k < E_) ? W_ih[row * E_ + k] : W_hh[row * H_ + (k - E_)];
        w1f[idx] = f2e4m3(v * 64.f);
    } else if (idx < 2097152u) {               // W_out-halves -> fp8*64
        u32 j = idx - 1572864u;
        u32 hb = j >> 18;
        u32 r  = j & 262143u;
        u32 ks = r >> 14;
        u32 r2 = r & 16383u;
        u32 vh2 = r2 >> 13;
        u32 r3 = r2 & 8191u;
        u32 wv = r3 >> 10, l = (r3 >> 4) & 63u, jj = (r3 >> 3) & 1u, e = r3 & 7u;
        u32 k = ks * 32u + ((l >> 4) << 3) + e;
        u32 v = hb * 512u + vh2 * 256u + wv * 32u + jj * 16u + (l & 15u);
        wof[j] = f2e4m3(W_out[v * H_ + k] * 64.f);
    } else if (idx < 2359296u) {               // W_emb K-halves -> fp8*64
        u32 j = idx - 2097152u;
        u32 hb = j >> 17;
        u32 r  = j & 131071u;
        u32 ksp = r >> 13;
        u32 r2 = r & 8191u;
        u32 wv = r2 >> 10, l = (r2 >> 4) & 63u, jj = (r2 >> 3) & 1u, e = r2 & 7u;
        u32 kv = hb * 512u + ksp * 32u + ((l >> 4) << 3) + e;
        u32 ce = wv * 32u + jj * 16u + (l & 15u);
        wef[j] = f2e4m3(W_emb[ce * V_ + kv] * 64.f);
    } else if (idx < 2361344u) {
        u32 j = idx - 2359296u;
        b1[j] = b_ih[j] + b_hh[j];
    } else if (idx < 2365440u) {
        flg[idx - 2361344u] = 0u;              // re-arm pair barriers each run
    }
}

// LDS layout (bytes) — activations + reductions only; weights go L2 -> VGPR
#define AEO   0u        // 16 x 776 fp8: [0,256) e*16, [256,768) h*16 (full)
#define XSO   12416u    // 16 x 520 fp8 xs-half = exp(z-m_loc)*256
#define RMX   20736u    // 16x8 f32 row-max partials
#define RSM   21248u    // 16x8 f32 row-sum partials
#define LDS_TOTAL 21760

#define WAITVM_(N) asm volatile("s_waitcnt vmcnt(" #N ")" ::: "memory")
#define WAITVM(N) WAITVM_(N)

__global__ __launch_bounds__(512, 2)
void lstm_fused(const float* __restrict__ x, const float* __restrict__ gum,
                const u8* __restrict__ w1f, const u8* __restrict__ wof,
                const u8* __restrict__ wef, const float* __restrict__ b1,
                const float* __restrict__ b_out, const float* __restrict__ b_emb,
                const float* __restrict__ sos, float* __restrict__ out,
                u8* __restrict__ hx, char* __restrict__ ms, char* __restrict__ ep,
                u32* __restrict__ flg)
{
    __shared__ __align__(16) char smem[LDS_TOTAL];

    const u32 tid = threadIdx.x;
    const u32 w   = tid >> 6;        // wave 0..7
    const u32 l   = tid & 63u;
    const u32 q   = l >> 4;
    const u32 col = l & 15u;

    const u32 bid = blockIdx.x;
    const u32 p   = bid & 127u;      // pair id (rows)
    const u32 hb  = bid >> 7;        // half: pairs (i, i+128) share an XCD
    const u32 ph  = 1u - hb;
    const int r0  = (int)(p << 4);

    u32* myf = flg + p * 32u + hb * 16u;
    u32* pef = flg + p * 32u + ph * 16u;
    u32 nbar = 0;

    const u32 wvl = (w << 10) + (l << 4);    // wave+lane slice inside a unit
    const u32 q8  = q << 3;
    const u32 colB776 = col * 776u;
    const u32 colB520 = col * 520u;

    const char* w1q = (const char*)w1f + (size_t)hb * 786432u;
    const char* woq = (const char*)wof + (size_t)hb * 262144u;
    const char* weq = (const char*)wef + (size_t)hb * 131072u;

#define PBAR() do { WAITVM(0); __syncthreads(); \
    if (tid == 0) { \
        __hip_atomic_fetch_add(myf, 1u, __ATOMIC_RELAXED, __HIP_MEMORY_SCOPE_AGENT); \
        while (__hip_atomic_load(pef, __ATOMIC_RELAXED, __HIP_MEMORY_SCOPE_AGENT) < nbar) \
            __builtin_amdgcn_s_sleep(2); \
    } \
    __syncthreads(); } while (0)

#define LDW1(U) (*(const i64x2*)(w1q + (size_t)((U) * 8192u) + wvl))
#define LDWO(U) (*(const i64x2*)(woq + (size_t)((U) * 8192u) + wvl))
#define LDWE(U) (*(const i64x2*)(weq + (size_t)((U) * 8192u) + wvl))

    // EOS v-half
    for (u32 i = tid; i < 16u * 512u; i += 512u) {
        u32 row = i >> 9, vl = i & 511u;
        __builtin_nontemporal_store((hb == 0u && vl == 0u) ? 1.f : 0.f,
            &out[((size_t)(r0 + (int)row) * 33 + 32) * V_ + hb * 512u + vl]);
    }
    // e0 = sos*16 (full), h0 = x*16 (full)
    for (u32 i = tid; i < 16u * 256u; i += 512u) {
        u32 row = i >> 8, k = i & 255u;
        *(u8*)(smem + AEO + row * 776u + k) = f2fp8(sos[k] * 16.f);
    }
    for (u32 i = tid; i < 16u * 512u; i += 512u) {
        u32 row = i >> 9, k = i & 511u;
        *(u8*)(smem + AEO + row * 776u + 256u + k) = f2fp8(x[(r0 + (int)row) * H_ + k] * 16.f);
    }

    // biases (own halves)
    float bia[2], bfa[2], bga[2], boa[2];
    #pragma unroll
    for (int jj = 0; jj < 2; ++jj) {
        int jg = (int)(hb * 256u + (w << 5) + ((u32)jj << 4) + col);
        bia[jj] = b1[jg];           bfa[jj] = b1[H_ + jg];
        bga[jj] = b1[2 * H_ + jg];  boa[jj] = b1[3 * H_ + jg];
    }
    float bov[2][2];
    #pragma unroll
    for (int v2 = 0; v2 < 2; ++v2)
        #pragma unroll
        for (int jj = 0; jj < 2; ++jj)
            bov[v2][jj] = b_out[hb * 512u + (u32)v2 * 256u + (w << 5) + ((u32)jj << 4) + col];
    float bem16[2];
    #pragma unroll
    for (int jj = 0; jj < 2; ++jj)
        bem16[jj] = b_emb[(w << 5) + ((u32)jj << 4) + col] * 16.f;

    float creg[2][4];
    #pragma unroll
    for (int jj = 0; jj < 2; ++jj)
        #pragma unroll
        for (int r = 0; r < 4; ++r) creg[jj][r] = 0.f;

    __syncthreads();

    const f32x4 fz = {0.f, 0.f, 0.f, 0.f};
    const float S1 = 1.f / 1024.f;
    const float CSC = 16.f / 16384.f;

    // phase-A ring prologue for t=0 (subsequent steps pre-issue before barrier 2)
    i64x2 rg[6];
    #pragma unroll
    for (int s = 0; s < 6; ++s) rg[s] = LDW1(s);

    #pragma unroll 1
    for (int t = 0; t < L_; ++t) {
        // ====== phase A: gate-half, VGPR ring-6 (96 units x 1 KB/wave) ======
        f32x4 acc[4][2];
        #pragma unroll
        for (int g = 0; g < 4; ++g) { acc[g][0] = fz; acc[g][1] = fz; }

        #pragma unroll
        for (int ks = 0; ks < 24; ++ks) {
            i64 a8 = *(const i64*)(smem + AEO + colB776 + ((u32)ks << 5) + q8);
            #pragma unroll
            for (int g = 0; g < 4; ++g) {
                const int u = ks * 4 + g, s = u % 6;
                acc[g][0] = __builtin_amdgcn_mfma_f32_16x16x32_fp8_fp8(a8, rg[s][0], acc[g][0], 0, 0, 0);
                acc[g][1] = __builtin_amdgcn_mfma_f32_16x16x32_fp8_fp8(a8, rg[s][1], acc[g][1], 0, 0, 0);
                if (u + 6 < 96) rg[s] = LDW1(u + 6);
            }
        }
        __syncthreads();            // AEO reads done before h overwrite

        // LSTM pointwise (own j-half)
        #pragma unroll
        for (int jj = 0; jj < 2; ++jj) {
            u32 jg = hb * 256u + (w << 5) + ((u32)jj << 4) + col;
            #pragma unroll
            for (int r = 0; r < 4; ++r) {
                float gi = sig_(acc[0][jj][r] * S1 + bia[jj]);
                float gf = sig_(acc[1][jj][r] * S1 + bfa[jj]);
                float gg = tanh_(acc[2][jj][r] * S1 + bga[jj]);
                float go = sig_(acc[3][jj][r] * S1 + boa[jj]);
                float c  = gf * creg[jj][r] + gi * gg;
                creg[jj][r] = c;
                float h = go * tanh_(c);
                *(u8*)(smem + AEO + ((q << 2) + (u32)r) * 776u + 256u + jg) = f2fp8(h * 16.f);
            }
        }
        __syncthreads();            // own h-half complete in AEO

        // export own h-half; B ring prologue hides under barrier 1
        {   u32 row = tid >> 5, off = (tid & 31u) << 3;
            u64 v = *(const u64*)(smem + AEO + row * 776u + 256u + hb * 256u + off);
            ag_st64(hx + (size_t)p * 8192u + row * 512u + hb * 256u + off, v);
        }
        i64x2 rb[6];
        #pragma unroll
        for (int s = 0; s < 6; ++s) rb[s] = LDWO(s);
        ++nbar; PBAR();             // barrier 1: h ready (B prologue completes here)
        {   u32 row = tid >> 5, off = (tid & 31u) << 3;
            u64 v = ag_ld64(hx + (size_t)p * 8192u + row * 512u + ph * 256u + off);
            *(u64*)(smem + AEO + row * 776u + 256u + ph * 256u + off) = v;
        }
        __syncthreads();            // full h in AEO

        // gumbel prefetch (latency hides under phase B's stream)
        const float* gt = gum + (size_t)t * (B_ * V_) + (size_t)r0 * V_;
        float gr[2][2][4];
        #pragma unroll
        for (int v2 = 0; v2 < 2; ++v2)
            #pragma unroll
            for (int jj = 0; jj < 2; ++jj) {
                u32 vg = hb * 512u + (u32)v2 * 256u + (w << 5) + ((u32)jj << 4) + col;
                #pragma unroll
                for (int r = 0; r < 4; ++r)
                    gr[v2][jj][r] = __builtin_nontemporal_load(&gt[((q << 2) + (u32)r) * V_ + vg]);
            }

        // ====== phase B: logit v-half, VGPR ring-6 (32 units) ======
        f32x4 accB[2][2];
        accB[0][0] = fz; accB[0][1] = fz; accB[1][0] = fz; accB[1][1] = fz;
        #pragma unroll
        for (int ks = 0; ks < 16; ++ks) {
            i64 a8 = *(const i64*)(smem + AEO + colB776 + 256u + ((u32)ks << 5) + q8);
            #pragma unroll
            for (int v2 = 0; v2 < 2; ++v2) {
                const int u = ks * 2 + v2, s = u % 6;
                accB[v2][0] = __builtin_amdgcn_mfma_f32_16x16x32_fp8_fp8(a8, rb[s][0], accB[v2][0], 0, 0, 0);
                accB[v2][1] = __builtin_amdgcn_mfma_f32_16x16x32_fp8_fp8(a8, rb[s][1], accB[v2][1], 0, 0, 0);
                if (u + 6 < 32) rb[s] = LDWO(u + 6);
            }
        }

        // z; LOCAL (half) max
        float m_loc[4], s_loc[4];
        #pragma unroll
        for (int r = 0; r < 4; ++r) m_loc[r] = -1e30f;
        #pragma unroll
        for (int v2 = 0; v2 < 2; ++v2)
            #pragma unroll
            for (int jj = 0; jj < 2; ++jj)
                #pragma unroll
                for (int r = 0; r < 4; ++r) {
                    float zz = accB[v2][jj][r] * S1 + bov[v2][jj] + gr[v2][jj][r];
                    accB[v2][jj][r] = zz;
                    m_loc[r] = fmaxf(m_loc[r], zz);
                }
        #pragma unroll
        for (int m = 1; m < 16; m <<= 1)
            #pragma unroll
            for (int r = 0; r < 4; ++r) m_loc[r] = fmaxf(m_loc[r], __shfl_xor(m_loc[r], m, 64));
        if (col == 0) {
            #pragma unroll
            for (int r = 0; r < 4; ++r)
                *(float*)(smem + RMX + ((((q << 2) + (u32)r) << 3) + w) * 4u) = m_loc[r];
        }
        __syncthreads();
        #pragma unroll
        for (int r = 0; r < 4; ++r) {
            float mm = -1e30f;
            #pragma unroll
            for (int ww = 0; ww < 8; ++ww)
                mm = fmaxf(mm, *(const float*)(smem + RMX + ((((q << 2) + (u32)r) << 3) + (u32)ww) * 4u));
            m_loc[r] = mm;
        }
        // C ring prologue hides under the rest of softmax
        i64x2 rc[6];
        #pragma unroll
        for (int s = 0; s < 6; ++s) rc[s] = LDWE(s);
        // eb = exp(z - m_loc); local sum; xs-half (local scale)
        float ps[4] = {0.f, 0.f, 0.f, 0.f};
        #pragma unroll
        for (int v2 = 0; v2 < 2; ++v2)
            #pragma unroll
            for (int jj = 0; jj < 2; ++jj) {
                u32 vl = (u32)v2 * 256u + (w << 5) + ((u32)jj << 4) + col;
                #pragma unroll
                for (int r = 0; r < 4; ++r) {
                    float Ee = __expf(accB[v2][jj][r] - m_loc[r]);
                    accB[v2][jj][r] = Ee;
                    ps[r] += Ee;
                    *(u8*)(smem + XSO + ((q << 2) + (u32)r) * 520u + vl) = f2fp8(Ee * 256.f);
                }
            }
        #pragma unroll
        for (int m = 1; m < 16; m <<= 1)
            #pragma unroll
            for (int r = 0; r < 4; ++r) ps[r] += __shfl_xor(ps[r], m, 64);
        if (col == 0) {
            #pragma unroll
            for (int r = 0; r < 4; ++r)
                *(float*)(smem + RSM + ((((q << 2) + (u32)r) << 3) + w) * 4u) = ps[r];
        }
        __syncthreads();            // xs + RSM visible block-wide
        #pragma unroll
        for (int r = 0; r < 4; ++r) {
            float ss = 0.f;
            #pragma unroll
            for (int ww = 0; ww < 8; ++ww)
                ss += *(const float*)(smem + RSM + ((((q << 2) + (u32)r) << 3) + (u32)ww) * 4u);
            s_loc[r] = ss;
        }

        // ====== phase C: partial e (own K-half, LOCAL xs), ring-6 (16) ======
        f32x4 accC[2];
        accC[0] = fz; accC[1] = fz;
        #pragma unroll
        for (int u = 0; u < 16; ++u) {
            const int s = u % 6;
            i64 xv = *(const i64*)(smem + XSO + colB520 + ((u32)u << 5) + q8);
            accC[0] = __builtin_amdgcn_mfma_f32_16x16x32_fp8_fp8(xv, rc[s][0], accC[0], 0, 0, 0);
            accC[1] = __builtin_amdgcn_mfma_f32_16x16x32_fp8_fp8(xv, rc[s][1], accC[1], 0, 0, 0);
            if (u + 6 < 16) rc[s] = LDWE(u + 6);
        }

        // exchange (m,s) + UNNORMALIZED e-partials in ONE barrier
        if (w == 0 && col == 0) {
            #pragma unroll
            for (int r = 0; r < 4; ++r) {
                u64 v = ((u64)f32b(s_loc[r]) << 32) | (u64)f32b(m_loc[r]);
                ag_st64(ms + (size_t)p * 256u + hb * 128u + (((q << 2) + (u32)r) << 3), v);
            }
        }
        #pragma unroll
        for (int r = 0; r < 4; ++r) {
            u32 row = (q << 2) + (u32)r;
            u32 pv = (u32)f2bf(accC[0][r] * CSC) | ((u32)f2bf(accC[1][r] * CSC) << 16);
            ag_st32(ep + (size_t)p * 16384u + hb * 8192u + (((row << 3) + w) << 6) + (col << 2), pv);
        }
        // next step's A ring prologue hides under barrier 2
        #pragma unroll
        for (int s = 0; s < 6; ++s) rg[s] = LDW1(s);
        ++nbar; PBAR();             // barrier 2: (m,s) + partials visible

        // global softmax factors
        float f0a[4], f1a[4], inva[4];
        #pragma unroll
        for (int r = 0; r < 4; ++r) {
            u64 v = ag_ld64(ms + (size_t)p * 256u + ph * 128u + (((q << 2) + (u32)r) << 3));
            float m_p = bf32((u32)v), s_p = bf32((u32)(v >> 32));
            float mg = fmaxf(m_loc[r], m_p);
            float f0 = __expf(m_loc[r] - mg), f1 = __expf(m_p - mg);
            float inv = 1.f / (s_loc[r] * f0 + s_p * f1);
            f0a[r] = f0; f1a[r] = f1; inva[r] = inv;
        }
        // out v-half (fp32 eb still live in accB)
        #pragma unroll
        for (int v2 = 0; v2 < 2; ++v2)
            #pragma unroll
            for (int jj = 0; jj < 2; ++jj) {
                u32 vg = hb * 512u + (u32)v2 * 256u + (w << 5) + ((u32)jj << 4) + col;
                #pragma unroll
                for (int r = 0; r < 4; ++r)
                    __builtin_nontemporal_store(accB[v2][jj][r] * f0a[r] * inva[r],
                        &out[((size_t)(r0 + (int)((q << 2) + (u32)r)) * 33 + t) * V_ + vg]);
            }
        // combine e-partials -> e
        #pragma unroll
        for (int r = 0; r < 4; ++r) {
            u32 row = (q << 2) + (u32)r;
            u32 pv = ag_ld32(ep + (size_t)p * 16384u + ph * 8192u + (((row << 3) + w) << 6) + (col << 2));
            #pragma unroll
            for (int jj = 0; jj < 2; ++jj) {
                float pe = bf32(((pv >> (16 * jj)) & 0xffffu) << 16);
                float e16 = (accC[jj][r] * CSC * f0a[r] + pe * f1a[r]) * inva[r] + bem16[jj];
                *(u8*)(smem + AEO + row * 776u + (w << 5) + ((u32)jj << 4) + col) = f2fp8(e16);
            }
        }
        __syncthreads();            // e complete before next step's phase A
    }
#undef PBAR
#undef LDW1
#undef LDWO
#undef LDWE
}

extern "C" void kernel_launch(void* const* d_in, const int* in_sizes, int n_in,
                              void* d_out, int out_size, void* d_ws, size_t ws_size,
                              hipStream_t stream) {
    const float* x     = (const float*)d_in[0];
    const float* gum   = (const float*)d_in[1];
    const float* W_ih  = (const float*)d_in[2];
    const float* W_hh  = (const float*)d_in[3];
    const float* b_ih  = (const float*)d_in[4];
    const float* b_hh  = (const float*)d_in[5];
    const float* W_out = (const float*)d_in[6];
    const float* b_out = (const float*)d_in[7];
    const float* W_emb = (const float*)d_in[8];
    const float* b_emb = (const float*)d_in[9];
    const float* sos   = (const float*)d_in[10];
    float* out = (float*)d_out;

    char* ws = (char*)d_ws;
    u8*    w1f = (u8*)(ws);                    // 1,572,864 B
    u8*    wof = (u8*)(ws + 1572864);          //   524,288 B
    u8*    wef = (u8*)(ws + 2097152);          //   262,144 B
    float* b1  = (float*)(ws + 2359296);       //     8,192 B
    u32*   flg = (u32*)(ws + 2367488);         //    16,384 B (pair barriers)
    u8*    hx  = (u8*)(ws + 2383872);          // 1,048,576 B (h exchange)
    char*  ms  = (char*)(ws + 3432448);        //    32,768 B (max/sum)
    char*  ep  = (char*)(ws + 3465216);        // 2,097,152 B (e partials)
    // total 5,562,368 B

    prep<<<9240, 256, 0, stream>>>(W_ih, W_hh, b_ih, b_hh, W_out, W_emb,
                                   w1f, wof, wef, b1, flg);
    lstm_fused<<<256, 512, 0, stream>>>(x, gum, w1f, wof, wef, b1,
                                        b_out, b_emb, sos, out,
                                        hx, ms, ep, flg);
}

// Round 16
// 865.546 us; speedup vs baseline: 2.2947x; 2.2947x over previous
//
#include <hip/hip_runtime.h>
#include <hip/hip_bf16.h>

#define B_   2048
#define V_   1024
#define H_   512
#define E_   256
#define L_   32

typedef __attribute__((ext_vector_type(4))) float f32x4;
typedef unsigned short u16;
typedef unsigned int   u32;
typedef unsigned char  u8;
typedef unsigned long long u64;
typedef long long      i64;

__device__ __forceinline__ u32 f32b(float x){ union{float f;u32 u;}v; v.f=x; return v.u; }
__device__ __forceinline__ float bf32(u32 u){ union{float f;u32 u;}v; v.u=u; return v.f; }
__device__ __forceinline__ u16 f2bf(float x) {
    u32 u = f32b(x);
    u32 r = u + 0x7fffu + ((u >> 16) & 1u);
    return (u16)(r >> 16);
}
// OCP e4m3fn encode, RNE, flush below 2^-6
__device__ __forceinline__ u8 f2e4m3(float x) {
    u32 u = f32b(x);
    u32 s = (u >> 24) & 0x80u;
    u32 a = u & 0x7fffffffu;
    if (a < 0x3c800000u) return (u8)s;
    if (a > 0x43e00000u) a = 0x43e00000u;
    u32 r = a + 0x000fffffu + ((a >> 20) & 1u);
    if (r > 0x43e00000u) r = 0x43e00000u;
    u32 ex = (r >> 23) - 120u;
    u32 mn = (r >> 20) & 7u;
    return (u8)(s | (ex << 3) | mn);
}
__device__ __forceinline__ u8 f2fp8(float x) {
#if __has_builtin(__builtin_amdgcn_cvt_pk_fp8_f32)
    return (u8)(__builtin_amdgcn_cvt_pk_fp8_f32(x, x, 0, false) & 0xff);
#else
    return f2e4m3(x);
#endif
}
__device__ __forceinline__ float sig_(float x)  { return 1.f / (1.f + __expf(-x)); }
__device__ __forceinline__ float tanh_(float x) { return 1.f - 2.f / (__expf(2.f * x) + 1.f); }

// agent-scope relaxed atomics (device-coherent; pair lives on same XCD L2)
__device__ __forceinline__ void ag_st64(void* p, u64 v) {
    __hip_atomic_store((u64*)p, v, __ATOMIC_RELAXED, __HIP_MEMORY_SCOPE_AGENT);
}
__device__ __forceinline__ u64 ag_ld64(const void* p) {
    return __hip_atomic_load((const u64*)p, __ATOMIC_RELAXED, __HIP_MEMORY_SCOPE_AGENT);
}
__device__ __forceinline__ void ag_st32(void* p, u32 v) {
    __hip_atomic_store((u32*)p, v, __ATOMIC_RELAXED, __HIP_MEMORY_SCOPE_AGENT);
}
__device__ __forceinline__ u32 ag_ld32(const void* p) {
    return __hip_atomic_load((const u32*)p, __ATOMIC_RELAXED, __HIP_MEMORY_SCOPE_AGENT);
}

// -------------------------------------------------------------------------
// Pair-split layouts, all fp8 e4m3 x64. Chunk = 8 KB = 8 waves x 1 KB;
// wave's 1 KB = 2 frags x 512 B. Block hb of a pair owns:
//  w1f[hb]: gates for j in [hb*256, hb*256+256): [hb 2][ks 24][g 4][wv 8][jj 2][l 64][e 8]
//      k = ks*32+(l>>4)*8+e,  row = g*512 + hb*256 + wv*32 + jj*16 + (l&15)
//  wof[hb]: logits v in [hb*512, +512): [hb 2][ks 16][vh2 2][wv 8][jj 2][l 64][e 8]
//      k = ks*32+(l>>4)*8+e,  v = hb*512 + vh2*256 + wv*32 + jj*16 + (l&15)
//  wef[hb]: K-half (vocab) [hb*512,+512): [hb 2][ksp 16][wv 8][jj 2][l 64][e 8]
//      kv = hb*512 + ksp*32+(l>>4)*8+e,  ce = wv*32 + jj*16 + (l&15)
//  b1 = b_ih + b_hh (fp32); then 4096 u32 pair-barrier flags (zeroed here
//  every run -> graph replays re-arm the barriers).
// -------------------------------------------------------------------------
__global__ void prep(const float* __restrict__ W_ih, const float* __restrict__ W_hh,
                     const float* __restrict__ b_ih, const float* __restrict__ b_hh,
                     const float* __restrict__ W_out, const float* __restrict__ W_emb,
                     u8* __restrict__ w1f, u8* __restrict__ wof, u8* __restrict__ wef,
                     float* __restrict__ b1, u32* __restrict__ flg)
{
    int idx = blockIdx.x * 256 + threadIdx.x;
    if (idx < 1572864) {                       // W1-halves -> fp8*64
        int e = idx & 7, l = (idx >> 3) & 63, jj = (idx >> 9) & 1, wv = (idx >> 10) & 7,
            g = (idx >> 13) & 3;
        int rest = idx >> 15;                  // [0,48)
        int hb = rest / 24, ks = rest % 24;
        int k = ks * 32 + ((l >> 4) << 3) + e;
        int row = g * 512 + hb * 256 + wv * 32 + jj * 16 + (l & 15);
        float v = (k < E_) ? W_ih[row * E_ + k] : W_hh[row * H_ + (k - E_)];
        w1f[idx] = f2e4m3(v * 64.f);
    } else if (idx < 2097152) {                // W_out-halves -> fp8*64
        int j = idx - 1572864;
        int e = j & 7, l = (j >> 3) & 63, jj = (j >> 9) & 1, wv = (j >> 10) & 7,
            vh2 = (j >> 13) & 1, ks = (j >> 14) & 15, hb = j >> 18;
        int k = ks * 32 + ((l >> 4) << 3) + e;
        int v = hb * 512 + vh2 * 256 + wv * 32 + jj * 16 + (l & 15);
        wof[j] = f2e4m3(W_out[v * H_ + k] * 64.f);
    } else if (idx < 2359296) {                // W_emb K-halves -> fp8*64
        int j = idx - 2097152;
        int e = j & 7, l = (j >> 3) & 63, jj = (j >> 9) & 1, wv = (j >> 10) & 7,
            ksp = (j >> 13) & 15, hb = j >> 17;
        int kv = hb * 512 + ksp * 32 + ((l >> 4) << 3) + e;
        int ce = wv * 32 + jj * 16 + (l & 15);
        wef[j] = f2e4m3(W_emb[ce * V_ + kv] * 64.f);
    } else if (idx < 2361344) {
        int j = idx - 2359296;
        b1[j] = b_ih[j] + b_hh[j];
    } else if (idx < 2365440) {
        flg[idx - 2361344] = 0u;               // re-arm pair barriers each run
    }
}

// LDS layout (bytes)
#define AEO   131072u   // 16 x 776 fp8: [0,256) e*16, [256,768) h*16 (full)
#define XSO   143488u   // 16 x 520 fp8 xs-half = exp(z-m_loc)*256
#define RMX   151808u   // 16x8 f32 row-max partials
#define RSM   152320u   // 16x8 f32 row-sum partials
#define LDS_TOTAL 152832  // ring 16 x 8192 + above

#define WAITVM_(N) asm volatile("s_waitcnt vmcnt(" #N ")" ::: "memory")
#define WAITVM(N) WAITVM_(N)

typedef const __attribute__((address_space(1))) void* gvp;
typedef __attribute__((address_space(3))) void* svp;

__device__ __forceinline__ void pbar(u32* myf, u32* pef, u32 n, u32 tid) {
    asm volatile("s_waitcnt vmcnt(0)" ::: "memory");   // all data stores acked
    __syncthreads();
    if (tid == 0) {
        __hip_atomic_fetch_add(myf, 1u, __ATOMIC_RELAXED, __HIP_MEMORY_SCOPE_AGENT);
        while (__hip_atomic_load(pef, __ATOMIC_RELAXED, __HIP_MEMORY_SCOPE_AGENT) < n)
            __builtin_amdgcn_s_sleep(2);
    }
    __syncthreads();
}

__global__ __launch_bounds__(512, 2)
void lstm_fused(const float* __restrict__ x, const float* __restrict__ gum,
                const u8* __restrict__ w1f, const u8* __restrict__ wof,
                const u8* __restrict__ wef, const float* __restrict__ b1,
                const float* __restrict__ b_out, const float* __restrict__ b_emb,
                const float* __restrict__ sos, float* __restrict__ out,
                u8* __restrict__ hx, char* __restrict__ ms, char* __restrict__ ep,
                u32* __restrict__ flg)
{
    extern __shared__ char smem[];

    const u32 tid = threadIdx.x;
    const u32 w   = tid >> 6;        // wave 0..7
    const u32 l   = tid & 63u;
    const u32 q   = l >> 4;
    const u32 col = l & 15u;

    const u32 bid = blockIdx.x;
    const u32 p   = bid & 127u;      // pair id (rows)
    const u32 hb  = bid >> 7;        // half: pairs (i, i+128) share an XCD
    const u32 ph  = 1u - hb;
    const int r0  = (int)(p << 4);

    u32* myf = flg + p * 32u + hb * 16u;
    u32* pef = flg + p * 32u + ph * 16u;
    u32 nbar = 0;

    const u32 wK  = w << 10;         // wave's 1 KB slice inside a chunk
    const u32 lB  = l << 4;
    const u32 l8  = l << 3;
    const u32 q8  = q << 3;
    const u32 colB776 = col * 776u;
    const u32 colB520 = col * 520u;

    const char* w1p = (const char*)w1f + (size_t)hb * 786432u;
    const char* wop = (const char*)wof + (size_t)hb * 262144u;
    const char* wep = (const char*)wef + (size_t)hb * 131072u;

#define ISS(BASE, C) do { u32 _c = (u32)(C); \
    u32 _o = (u32)__builtin_amdgcn_readfirstlane((int)(((_c & 15u) << 13) + wK)); \
    __builtin_amdgcn_global_load_lds((gvp)((BASE) + ((size_t)_c << 13) + wK + lB), \
                                     (svp)(smem + _o), 16, 0, 0); } while (0)

#define CONSA(G, C) { const char* _fb = smem + (((u32)(C) & 15u) << 13) + wK + l8; \
    acc[G][0] = __builtin_amdgcn_mfma_f32_16x16x32_fp8_fp8(a8, *(const i64*)(_fb), acc[G][0], 0, 0, 0); \
    acc[G][1] = __builtin_amdgcn_mfma_f32_16x16x32_fp8_fp8(a8, *(const i64*)(_fb + 512u), acc[G][1], 0, 0, 0); }

#define CONSB(V2, C, A8) { const char* _fb = smem + (((u32)(C) & 15u) << 13) + wK + l8; \
    accB[V2][0] = __builtin_amdgcn_mfma_f32_16x16x32_fp8_fp8(A8, *(const i64*)(_fb), accB[V2][0], 0, 0, 0); \
    accB[V2][1] = __builtin_amdgcn_mfma_f32_16x16x32_fp8_fp8(A8, *(const i64*)(_fb + 512u), accB[V2][1], 0, 0, 0); }

#define CONSC(C) { const char* _fb = smem + (((u32)(C) & 15u) << 13) + wK + l8; \
    i64 _x = *(const i64*)(smem + XSO + colB520 + (((u32)(C)) << 5) + q8); \
    accC[0] = __builtin_amdgcn_mfma_f32_16x16x32_fp8_fp8(_x, *(const i64*)(_fb), accC[0], 0, 0, 0); \
    accC[1] = __builtin_amdgcn_mfma_f32_16x16x32_fp8_fp8(_x, *(const i64*)(_fb + 512u), accC[1], 0, 0, 0); }

    // EOS v-half
    for (u32 i = tid; i < 16u * 512u; i += 512u) {
        u32 row = i >> 9, vl = i & 511u;
        __builtin_nontemporal_store((hb == 0u && vl == 0u) ? 1.f : 0.f,
            &out[((size_t)(r0 + (int)row) * 33 + 32) * V_ + hb * 512u + vl]);
    }
    // e0 = sos*16 (full), h0 = x*16 (full)
    for (u32 i = tid; i < 16u * 256u; i += 512u) {
        u32 row = i >> 8, k = i & 255u;
        *(u8*)(smem + AEO + row * 776u + k) = f2fp8(sos[k] * 16.f);
    }
    for (u32 i = tid; i < 16u * 512u; i += 512u) {
        u32 row = i >> 9, k = i & 511u;
        *(u8*)(smem + AEO + row * 776u + 256u + k) = f2fp8(x[(r0 + (int)row) * H_ + k] * 16.f);
    }

    // biases (own halves)
    float bia[2], bfa[2], bga[2], boa[2];
    #pragma unroll
    for (int jj = 0; jj < 2; ++jj) {
        int jg = (int)(hb * 256u + (w << 5) + ((u32)jj << 4) + col);
        bia[jj] = b1[jg];           bfa[jj] = b1[H_ + jg];
        bga[jj] = b1[2 * H_ + jg];  boa[jj] = b1[3 * H_ + jg];
    }
    float bov[2][2];
    #pragma unroll
    for (int v2 = 0; v2 < 2; ++v2)
        #pragma unroll
        for (int jj = 0; jj < 2; ++jj)
            bov[v2][jj] = b_out[hb * 512u + (u32)v2 * 256u + (w << 5) + ((u32)jj << 4) + col];
    float bem16[2];
    #pragma unroll
    for (int jj = 0; jj < 2; ++jj)
        bem16[jj] = b_emb[(w << 5) + ((u32)jj << 4) + col] * 16.f;

    float creg[2][4];
    #pragma unroll
    for (int jj = 0; jj < 2; ++jj)
        #pragma unroll
        for (int r = 0; r < 4; ++r) creg[jj][r] = 0.f;

    __syncthreads();

    const f32x4 fz = {0.f, 0.f, 0.f, 0.f};
    const float S1 = 1.f / 1024.f;

    // phase-A prologue for t=0 (subsequent steps pre-issue before barrier 2)
    ISS(w1p, 0);  ISS(w1p, 1);  ISS(w1p, 2);  ISS(w1p, 3);  ISS(w1p, 4);
    ISS(w1p, 5);  ISS(w1p, 6);  ISS(w1p, 7);  ISS(w1p, 8);  ISS(w1p, 9);
    ISS(w1p, 10); ISS(w1p, 11); ISS(w1p, 12); ISS(w1p, 13); ISS(w1p, 14);

    #pragma unroll 1
    for (int t = 0; t < L_; ++t) {
        // ====== phase A: gate-half, ring-16 of 8 KB chunks (96) ======
        f32x4 acc[4][2];
        #pragma unroll
        for (int g = 0; g < 4; ++g) { acc[g][0] = fz; acc[g][1] = fz; }

        #pragma unroll 1
        for (int ks = 0; ks < 20; ++ks) {
            i64 a8 = *(const i64*)(smem + AEO + colB776 + ((u32)ks << 5) + q8);
            int c0 = ks << 2;
            WAITVM(11);
            CONSA(0, c0); CONSA(1, c0 + 1); CONSA(2, c0 + 2); CONSA(3, c0 + 3);
            ISS(w1p, c0 + 15); ISS(w1p, c0 + 16); ISS(w1p, c0 + 17); ISS(w1p, c0 + 18);
        }
        {   i64 a8 = *(const i64*)(smem + AEO + colB776 + (20u << 5) + q8);
            WAITVM(11); CONSA(0, 80); CONSA(1, 81); CONSA(2, 82); CONSA(3, 83); ISS(w1p, 95); }
        {   i64 a8 = *(const i64*)(smem + AEO + colB776 + (21u << 5) + q8);
            WAITVM(8);  CONSA(0, 84); CONSA(1, 85); CONSA(2, 86); CONSA(3, 87); }
        {   i64 a8 = *(const i64*)(smem + AEO + colB776 + (22u << 5) + q8);
            WAITVM(4);  CONSA(0, 88); CONSA(1, 89); CONSA(2, 90); CONSA(3, 91); }
        {   i64 a8 = *(const i64*)(smem + AEO + colB776 + (23u << 5) + q8);
            WAITVM(0);  CONSA(0, 92); CONSA(1, 93); CONSA(2, 94); CONSA(3, 95); }
        __syncthreads();            // AEO reads done before h overwrite

        // LSTM pointwise (own j-half)
        #pragma unroll
        for (int jj = 0; jj < 2; ++jj) {
            u32 jg = hb * 256u + (w << 5) + ((u32)jj << 4) + col;
            #pragma unroll
            for (int r = 0; r < 4; ++r) {
                float gi = sig_(acc[0][jj][r] * S1 + bia[jj]);
                float gf = sig_(acc[1][jj][r] * S1 + bfa[jj]);
                float gg = tanh_(acc[2][jj][r] * S1 + bga[jj]);
                float go = sig_(acc[3][jj][r] * S1 + boa[jj]);
                float c  = gf * creg[jj][r] + gi * gg;
                creg[jj][r] = c;
                float h = go * tanh_(c);
                *(u8*)(smem + AEO + ((q << 2) + (u32)r) * 776u + 256u + jg) = f2fp8(h * 16.f);
            }
        }
        __syncthreads();            // own h-half complete in AEO

        // export own h-half; B-prologue + gumbel prefetch hide under barrier 1
        {   u32 row = tid >> 5, off = (tid & 31u) << 3;
            u64 v = *(const u64*)(smem + AEO + row * 776u + 256u + hb * 256u + off);
            ag_st64(hx + (size_t)p * 8192u + row * 512u + hb * 256u + off, v);
        }
        ISS(wop, 0);  ISS(wop, 1);  ISS(wop, 2);  ISS(wop, 3);  ISS(wop, 4);
        ISS(wop, 5);  ISS(wop, 6);  ISS(wop, 7);  ISS(wop, 8);  ISS(wop, 9);
        ISS(wop, 10); ISS(wop, 11); ISS(wop, 12); ISS(wop, 13); ISS(wop, 14);
        const float* gt = gum + (size_t)t * (B_ * V_) + (size_t)r0 * V_;
        float gr[2][2][4];
        #pragma unroll
        for (int v2 = 0; v2 < 2; ++v2)
            #pragma unroll
            for (int jj = 0; jj < 2; ++jj) {
                u32 vg = hb * 512u + (u32)v2 * 256u + (w << 5) + ((u32)jj << 4) + col;
                #pragma unroll
                for (int r = 0; r < 4; ++r)
                    gr[v2][jj][r] = __builtin_nontemporal_load(&gt[((q << 2) + (u32)r) * V_ + vg]);
            }
        ++nbar; pbar(myf, pef, nbar, tid);     // barrier 1: h ready
        {   u32 row = tid >> 5, off = (tid & 31u) << 3;
            u64 v = ag_ld64(hx + (size_t)p * 8192u + row * 512u + ph * 256u + off);
            *(u64*)(smem + AEO + row * 776u + 256u + ph * 256u + off) = v;
        }
        __syncthreads();            // full h in AEO

        // ====== phase B: logit v-half, ring-16 (32 chunks) ======
        f32x4 accB[2][2];
        accB[0][0] = fz; accB[0][1] = fz; accB[1][0] = fz; accB[1][1] = fz;
        #pragma unroll 1
        for (int g = 0; g < 4; ++g) {
            i64 a80 = *(const i64*)(smem + AEO + colB776 + 256u + (((u32)g << 1) << 5) + q8);
            i64 a81 = *(const i64*)(smem + AEO + colB776 + 256u + ((((u32)g << 1) | 1u) << 5) + q8);
            int c0 = g << 2;
            WAITVM(11);
            CONSB(0, c0, a80); CONSB(1, c0 + 1, a80);
            CONSB(0, c0 + 2, a81); CONSB(1, c0 + 3, a81);
            ISS(wop, c0 + 15); ISS(wop, c0 + 16); ISS(wop, c0 + 17); ISS(wop, c0 + 18);
        }
        {   i64 a80 = *(const i64*)(smem + AEO + colB776 + 256u + (8u << 5) + q8);
            i64 a81 = *(const i64*)(smem + AEO + colB776 + 256u + (9u << 5) + q8);
            WAITVM(11); CONSB(0, 16, a80); CONSB(1, 17, a80); CONSB(0, 18, a81); CONSB(1, 19, a81);
            ISS(wop, 31); }
        {   i64 a80 = *(const i64*)(smem + AEO + colB776 + 256u + (10u << 5) + q8);
            i64 a81 = *(const i64*)(smem + AEO + colB776 + 256u + (11u << 5) + q8);
            WAITVM(8);  CONSB(0, 20, a80); CONSB(1, 21, a80); CONSB(0, 22, a81); CONSB(1, 23, a81); }
        {   i64 a80 = *(const i64*)(smem + AEO + colB776 + 256u + (12u << 5) + q8);
            i64 a81 = *(const i64*)(smem + AEO + colB776 + 256u + (13u << 5) + q8);
            WAITVM(4);  CONSB(0, 24, a80); CONSB(1, 25, a80); CONSB(0, 26, a81); CONSB(1, 27, a81); }
        {   i64 a80 = *(const i64*)(smem + AEO + colB776 + 256u + (14u << 5) + q8);
            i64 a81 = *(const i64*)(smem + AEO + colB776 + 256u + (15u << 5) + q8);
            WAITVM(0);  CONSB(0, 28, a80); CONSB(1, 29, a80); CONSB(0, 30, a81); CONSB(1, 31, a81); }

        // z; LOCAL (half) max — no cross-block exchange needed before phase C
        float m_loc[4], s_loc[4];
        #pragma unroll
        for (int r = 0; r < 4; ++r) m_loc[r] = -1e30f;
        #pragma unroll
        for (int v2 = 0; v2 < 2; ++v2)
            #pragma unroll
            for (int jj = 0; jj < 2; ++jj)
                #pragma unroll
                for (int r = 0; r < 4; ++r) {
                    float zz = accB[v2][jj][r] * S1 + bov[v2][jj] + gr[v2][jj][r];
                    accB[v2][jj][r] = zz;
                    m_loc[r] = fmaxf(m_loc[r], zz);
                }
        #pragma unroll
        for (int m = 1; m < 16; m <<= 1)
            #pragma unroll
            for (int r = 0; r < 4; ++r) m_loc[r] = fmaxf(m_loc[r], __shfl_xor(m_loc[r], m, 64));
        if (col == 0) {
            #pragma unroll
            for (int r = 0; r < 4; ++r)
                *(float*)(smem + RMX + ((((q << 2) + (u32)r) << 3) + w) * 4u) = m_loc[r];
        }
        __syncthreads();
        #pragma unroll
        for (int r = 0; r < 4; ++r) {
            float mm = -1e30f;
            #pragma unroll
            for (int ww = 0; ww < 8; ++ww)
                mm = fmaxf(mm, *(const float*)(smem + RMX + ((((q << 2) + (u32)r) << 3) + (u32)ww) * 4u));
            m_loc[r] = mm;
        }
        // C-prologue hides under the rest of softmax
        ISS(wep, 0);  ISS(wep, 1);  ISS(wep, 2);  ISS(wep, 3);  ISS(wep, 4);
        ISS(wep, 5);  ISS(wep, 6);  ISS(wep, 7);  ISS(wep, 8);  ISS(wep, 9);
        ISS(wep, 10); ISS(wep, 11); ISS(wep, 12); ISS(wep, 13); ISS(wep, 14);
        // eb = exp(z - m_loc); local sum; xs-half (local scale)
        float ps[4] = {0.f, 0.f, 0.f, 0.f};
        #pragma unroll
        for (int v2 = 0; v2 < 2; ++v2)
            #pragma unroll
            for (int jj = 0; jj < 2; ++jj) {
                u32 vl = (u32)v2 * 256u + (w << 5) + ((u32)jj << 4) + col;
                #pragma unroll
                for (int r = 0; r < 4; ++r) {
                    float Ee = __expf(accB[v2][jj][r] - m_loc[r]);
                    accB[v2][jj][r] = Ee;
                    ps[r] += Ee;
                    *(u8*)(smem + XSO + ((q << 2) + (u32)r) * 520u + vl) = f2fp8(Ee * 256.f);
                }
            }
        #pragma unroll
        for (int m = 1; m < 16; m <<= 1)
            #pragma unroll
            for (int r = 0; r < 4; ++r) ps[r] += __shfl_xor(ps[r], m, 64);
        if (col == 0) {
            #pragma unroll
            for (int r = 0; r < 4; ++r)
                *(float*)(smem + RSM + ((((q << 2) + (u32)r) << 3) + w) * 4u) = ps[r];
        }
        __syncthreads();            // xs + RSM visible block-wide
        #pragma unroll
        for (int r = 0; r < 4; ++r) {
            float ss = 0.f;
            #pragma unroll
            for (int ww = 0; ww < 8; ++ww)
                ss += *(const float*)(smem + RSM + ((((q << 2) + (u32)r) << 3) + (u32)ww) * 4u);
            s_loc[r] = ss;
        }

        // ====== phase C: partial e (own K-half, LOCAL xs), ring-16 (16) ======
        f32x4 accC[2];
        accC[0] = fz; accC[1] = fz;
        WAITVM(11); CONSC(0);  CONSC(1);  CONSC(2);  CONSC(3);  ISS(wep, 15);
        WAITVM(8);  CONSC(4);  CONSC(5);  CONSC(6);  CONSC(7);
        WAITVM(4);  CONSC(8);  CONSC(9);  CONSC(10); CONSC(11);
        WAITVM(0);  CONSC(12); CONSC(13); CONSC(14); CONSC(15);

        // exchange (m,s) + UNNORMALIZED e-partials in ONE barrier
        float part[2][4];
        #pragma unroll
        for (int jj = 0; jj < 2; ++jj)
            #pragma unroll
            for (int r = 0; r < 4; ++r)
                part[jj][r] = accC[jj][r] * (16.f / 16384.f);   // 16 * sum(eb*W)
        if (w == 0 && col == 0) {
            #pragma unroll
            for (int r = 0; r < 4; ++r) {
                u64 v = ((u64)f32b(s_loc[r]) << 32) | (u64)f32b(m_loc[r]);
                ag_st64(ms + (size_t)p * 256u + hb * 128u + (((q << 2) + (u32)r) << 3), v);
            }
        }
        #pragma unroll
        for (int r = 0; r < 4; ++r) {
            u32 row = (q << 2) + (u32)r;
            u32 pv = (u32)f2bf(part[0][r]) | ((u32)f2bf(part[1][r]) << 16);
            ag_st32(ep + (size_t)p * 16384u + hb * 8192u + (((row << 3) + w) << 6) + (col << 2), pv);
        }
        // next step's A-prologue hides under barrier 2
        ISS(w1p, 0);  ISS(w1p, 1);  ISS(w1p, 2);  ISS(w1p, 3);  ISS(w1p, 4);
        ISS(w1p, 5);  ISS(w1p, 6);  ISS(w1p, 7);  ISS(w1p, 8);  ISS(w1p, 9);
        ISS(w1p, 10); ISS(w1p, 11); ISS(w1p, 12); ISS(w1p, 13); ISS(w1p, 14);
        ++nbar; pbar(myf, pef, nbar, tid);     // barrier 2: (m,s) + partials

        // global softmax factors
        float f0a[4], f1a[4], inva[4];
        #pragma unroll
        for (int r = 0; r < 4; ++r) {
            u64 v = ag_ld64(ms + (size_t)p * 256u + ph * 128u + (((q << 2) + (u32)r) << 3));
            float m_p = bf32((u32)v), s_p = bf32((u32)(v >> 32));
            float mg = fmaxf(m_loc[r], m_p);
            float f0 = __expf(m_loc[r] - mg), f1 = __expf(m_p - mg);
            float inv = 1.f / (s_loc[r] * f0 + s_p * f1);
            f0a[r] = f0; f1a[r] = f1; inva[r] = inv;
        }
        // out v-half (fp32 eb still live in accB)
        #pragma unroll
        for (int v2 = 0; v2 < 2; ++v2)
            #pragma unroll
            for (int jj = 0; jj < 2; ++jj) {
                u32 vg = hb * 512u + (u32)v2 * 256u + (w << 5) + ((u32)jj << 4) + col;
                #pragma unroll
                for (int r = 0; r < 4; ++r)
                    __builtin_nontemporal_store(accB[v2][jj][r] * f0a[r] * inva[r],
                        &out[((size_t)(r0 + (int)((q << 2) + (u32)r)) * 33 + t) * V_ + vg]);
            }
        // combine e-partials -> e
        #pragma unroll
        for (int r = 0; r < 4; ++r) {
            u32 row = (q << 2) + (u32)r;
            u32 pv = ag_ld32(ep + (size_t)p * 16384u + ph * 8192u + (((row << 3) + w) << 6) + (col << 2));
            #pragma unroll
            for (int jj = 0; jj < 2; ++jj) {
                float pe = bf32(((pv >> (16 * jj)) & 0xffffu) << 16);
                float e16 = (part[jj][r] * f0a[r] + pe * f1a[r]) * inva[r] + bem16[jj];
                *(u8*)(smem + AEO + row * 776u + (w << 5) + ((u32)jj << 4) + col) = f2fp8(e16);
            }
        }
        __syncthreads();            // e complete before next step's phase A
    }
#undef ISS
#undef CONSA
#undef CONSB
#undef CONSC
}

extern "C" void kernel_launch(void* const* d_in, const int* in_sizes, int n_in,
                              void* d_out, int out_size, void* d_ws, size_t ws_size,
                              hipStream_t stream) {
    const float* x     = (const float*)d_in[0];
    const float* gum   = (const float*)d_in[1];
    const float* W_ih  = (const float*)d_in[2];
    const float* W_hh  = (const float*)d_in[3];
    const float* b_ih  = (const float*)d_in[4];
    const float* b_hh  = (const float*)d_in[5];
    const float* W_out = (const float*)d_in[6];
    const float* b_out = (const float*)d_in[7];
    const float* W_emb = (const float*)d_in[8];
    const float* b_emb = (const float*)d_in[9];
    const float* sos   = (const float*)d_in[10];
    float* out = (float*)d_out;

    char* ws = (char*)d_ws;
    u8*    w1f = (u8*)(ws);                    // 1,572,864 B
    u8*    wof = (u8*)(ws + 1572864);          //   524,288 B
    u8*    wef = (u8*)(ws + 2097152);          //   262,144 B
    float* b1  = (float*)(ws + 2359296);       //     8,192 B
    u32*   flg = (u32*)(ws + 2367488);         //    16,384 B (pair barriers)
    u8*    hx  = (u8*)(ws + 2383872);          // 1,048,576 B (h exchange)
    char*  ms  = (char*)(ws + 3432448);        //    32,768 B (max/sum)
    char*  ep  = (char*)(ws + 3465216);        // 2,097,152 B (e partials)
    // total 5,562,368 B

    hipFuncSetAttribute((const void*)lstm_fused,
                        hipFuncAttributeMaxDynamicSharedMemorySize, LDS_TOTAL);

    prep<<<9240, 256, 0, stream>>>(W_ih, W_hh, b_ih, b_hh, W_out, W_emb,
                                   w1f, wof, wef, b1, flg);
    lstm_fused<<<256, 512, LDS_TOTAL, stream>>>(x, gum, w1f, wof, wef, b1,
                                                b_out, b_emb, sos, out,
                                                hx, ms, ep, flg);
}